// Round 11
// baseline (182.083 us; speedup 1.0000x reference)
//
#include <hip/hip_runtime.h>
#include <hip/hip_bf16.h>

// Problem constants
#define B_ 4
#define DIM_ 256
#define N_ 2048
#define M_ 2048
#define HEADS_ 8
#define DHEAD_ 64
#define DINNER_ 512

typedef __attribute__((ext_vector_type(8))) short short8;
typedef __attribute__((ext_vector_type(4))) short short4v;
typedef __attribute__((ext_vector_type(4))) float floatx4;
typedef __attribute__((ext_vector_type(4))) _Float16 half4;
typedef __attribute__((ext_vector_type(8))) _Float16 half8;

#if defined(__has_builtin)
#if __has_builtin(__builtin_amdgcn_global_load_lds)
#define HAS_DMA 1
#endif
#endif

typedef __attribute__((address_space(1))) const void gvoid_t;
typedef __attribute__((address_space(3))) void lvoid_t;

// |C2| = 0.125 * log2(e); folded into Q and K bf16 planes so attention's
// inner loop computes pv = exp2(-sqrt(d2')) with zero extra multiplies.
#define CQ_ 0.18033688011112042f
#define NEG2CQ_ (-0.36067376022224084f)
#define EPS2_ 3.25213893e-14f  // 1e-12 * CQ^2

__device__ inline short bf16r(float x) {  // RNE f32->bf16 (bit form)
  unsigned u = __float_as_uint(x);
  unsigned r = (u + 0x7fffu + ((u >> 16) & 1u)) >> 16;
  return (short)r;
}
__device__ inline float bf2f(short b) {
  return __uint_as_float(((unsigned)(unsigned short)b) << 16);
}

// ---------------------------------------------------------------------------
// Kernel 0 (fused preproc): bid<768 -> W split (whi/wlo bf16 planes of
// W*gamma); bid>=768 -> channel RMSNorm -> bf16 transposed for fmap+context.
// colnorm global reads float4-vectorized (R8, verified).
// ---------------------------------------------------------------------------
__global__ __launch_bounds__(256) void preproc_kernel(
    const float* __restrict__ Wq, const float* __restrict__ Wkv,
    const float* __restrict__ Wout, const float* __restrict__ gamma,
    const float* __restrict__ gctx, short* __restrict__ whi,
    short* __restrict__ wlo, const float* __restrict__ xf,
    const float* __restrict__ xc, short* __restrict__ xtf,
    short* __restrict__ xtc) {
  const int bid = blockIdx.x;
  const int tid = threadIdx.x;

  __shared__ float4 red4[16][16];
  __shared__ float scl[64];
  __shared__ float t[64][65];

  if (bid < 768) {
    // ---- W split part ----
    const int y = bid >> 8;  // 0..2
    const int gsz[3] = {32768, 65536, 32768};  // float4 groups per matrix
    const int goff[3] = {0, 131072, 393216};   // element offset in planes
    int gidx = (bid & 255) * 256 + tid;
    if (gidx >= gsz[y]) return;
    const float* W = (y == 0) ? Wq : (y == 1) ? Wkv : Wout;
    const int cmask = (y == 2) ? 511 : 255;
    int e0 = gidx * 4;
    int c = e0 & cmask;
    float4 wv = *(const float4*)&W[e0];
    if (y < 2) {
      const float* g = (y == 0) ? gamma : gctx;
      float4 g4 = *(const float4*)&g[c];
      wv.x *= g4.x; wv.y *= g4.y; wv.z *= g4.z; wv.w *= g4.w;
    }
    float vv[4] = {wv.x, wv.y, wv.z, wv.w};
    short4v hi, lo;
#pragma unroll
    for (int e = 0; e < 4; ++e) {
      short hb = bf16r(vv[e]);
      hi[e] = hb;
      lo[e] = bf16r(vv[e] - bf2f(hb));
    }
    *(short4v*)&whi[goff[y] + e0] = hi;
    *(short4v*)&wlo[goff[y] + e0] = lo;
    return;
  }

  // ---- colnorm part (float4-vectorized loads) ----
  const int cid = bid - 768;              // 0..255
  const int NN = 2048;
  const int z = cid >> 7;                 // 0..1
  const int b = (cid >> 5) & 3;           // 0..3
  const int xblk = cid & 31;              // 0..31
  const float* x = (z == 0) ? xf : xc;
  short* xt = (z == 0) ? xtf : xtc;
  const int tx4 = tid & 15, tyc = tid >> 4;  // n-quad 0..15, channel 0..15
  const int n0 = xblk * 64;
  const float* xb = x + (size_t)b * 256 * NN;

  float4 ssq4 = {0.f, 0.f, 0.f, 0.f};
  for (int c = tyc; c < 256; c += 16) {
    float4 v = *(const float4*)&xb[(size_t)c * NN + n0 + tx4 * 4];
    ssq4.x += v.x * v.x; ssq4.y += v.y * v.y;
    ssq4.z += v.z * v.z; ssq4.w += v.w * v.w;
  }
  red4[tyc][tx4] = ssq4;
  __syncthreads();
  if (tid < 16) {
    float4 s = red4[0][tid];
#pragma unroll
    for (int g = 1; g < 16; ++g) {
      float4 v = red4[g][tid];
      s.x += v.x; s.y += v.y; s.z += v.z; s.w += v.w;
    }
    scl[tid * 4 + 0] = 16.0f / fmaxf(sqrtf(s.x), 1e-12f);
    scl[tid * 4 + 1] = 16.0f / fmaxf(sqrtf(s.y), 1e-12f);
    scl[tid * 4 + 2] = 16.0f / fmaxf(sqrtf(s.z), 1e-12f);
    scl[tid * 4 + 3] = 16.0f / fmaxf(sqrtf(s.w), 1e-12f);
  }
  const int row = tid >> 2, cg = tid & 3;
  for (int c0 = 0; c0 < 256; c0 += 64) {
    __syncthreads();
    for (int cc = tyc; cc < 64; cc += 16) {
      float4 v = *(const float4*)&xb[(size_t)(c0 + cc) * NN + n0 + tx4 * 4];
      t[cc][tx4 * 4 + 0] = v.x;
      t[cc][tx4 * 4 + 1] = v.y;
      t[cc][tx4 * 4 + 2] = v.z;
      t[cc][tx4 * 4 + 3] = v.w;
    }
    __syncthreads();
    float sc = scl[row];
    short8 o0v, o1v;
#pragma unroll
    for (int e = 0; e < 8; ++e) {
      o0v[e] = bf16r(t[cg * 16 + e][row] * sc);
      o1v[e] = bf16r(t[cg * 16 + 8 + e][row] * sc);
    }
    size_t base = ((size_t)b * NN + n0 + row) * 256 + c0 + cg * 16;
    *(short8*)&xt[base] = o0v;
    *(short8*)&xt[base + 8] = o1v;
  }
}

// ---------------------------------------------------------------------------
// Kernel 2: fused Q + KV projection MFMA GEMM (one launch).
// grid (16, 12, B): y<4 -> q-proj; y>=4 -> kv-proj (K-part / V-part).
// R11: attn-style 1-barrier DOUBLE-BUFFERED DMA staging -- stage(c+1) is
// issued right after the barrier that drains stage(c), so the next tile's
// L2 latency hides under this tile's MFMA (was: 2 barriers/iter, zero
// overlap -- the R10-neutral result showed instr count wasn't the cost;
// the serial drain was). LDS 48KB (2x24KB dbuf, epilogue slabs overlay),
// 3 blocks/CU (unchanged -- grid is the occupancy limiter).
// Swizzle (rule #21): linear LDS dest, global chunk (l&3)^((row>>1)&3),
// read slot quad^((row>>1)&3). Epilogues: LDS-staged coalesced (R7/R10).
// ---------------------------------------------------------------------------
__global__ __launch_bounds__(256) void qkv_gemm_kernel(
    const short* __restrict__ whi, const short* __restrict__ wlo,
    const short* __restrict__ fmap_t, const short* __restrict__ ctx_t,
    short* __restrict__ qb, short* __restrict__ kc, _Float16* __restrict__ vc,
    const int* __restrict__ maskp, float* __restrict__ k2m) {
  const int b = blockIdx.z;
  const int y = blockIdx.y;
  const bool isq = (y < 4);
  const int o0 = (isq ? y : y - 4) * 128;
  const int n0 = blockIdx.x * 128;
  const short* Wh = whi + (isq ? 0 : 131072);
  const short* Wl = wlo + (isq ? 0 : 131072);
  const short* Xt = isq ? fmap_t : ctx_t;

  const int tid = threadIdx.x;
  const int w = tid >> 6, l = tid & 63, quad = l >> 4, l15 = l & 15;
  const int wo = (w >> 1) * 64, wn = (w & 1) * 64;

  // dbuf p at smem+p*24576: lWh +0, lWl +8192, lXb +16384 (each [128][32]).
  // Epilogue: 4 wave slabs of [64][72] shorts = 36864B (overlay).
  __shared__ __align__(16) char smem[49152];

  floatx4 acc[4][4];
#pragma unroll
  for (int ot = 0; ot < 4; ++ot)
#pragma unroll
    for (int nt = 0; nt < 4; ++nt)
#pragma unroll
      for (int r = 0; r < 4; ++r) acc[ot][nt][r] = 0.f;

  auto stageT = [&](int c0, int p) {
    char* base = smem + p * 24576;
    short* dWh = (short*)base;
    short* dWl = (short*)(base + 8192);
    short* dXb = (short*)(base + 16384);
#pragma unroll
    for (int half = 0; half < 2; ++half) {
      int r0 = w * 32 + half * 16;
      int row = r0 + (l >> 2);
      int chunk = (l & 3) ^ ((row >> 1) & 3);
      size_t wsrc = (size_t)(o0 + row) * 256 + c0 + chunk * 8;
      size_t xsrc = ((size_t)b * 2048 + n0 + row) * 256 + c0 + chunk * 8;
#ifdef HAS_DMA
      __builtin_amdgcn_global_load_lds((gvoid_t*)&Wh[wsrc],
                                       (lvoid_t*)&dWh[r0 * 32], 16, 0, 0);
      __builtin_amdgcn_global_load_lds((gvoid_t*)&Wl[wsrc],
                                       (lvoid_t*)&dWl[r0 * 32], 16, 0, 0);
      __builtin_amdgcn_global_load_lds((gvoid_t*)&Xt[xsrc],
                                       (lvoid_t*)&dXb[r0 * 32], 16, 0, 0);
#else
      *(short8*)&dWh[row * 32 + (l & 3) * 8] = *(const short8*)&Wh[wsrc];
      *(short8*)&dWl[row * 32 + (l & 3) * 8] = *(const short8*)&Wl[wsrc];
      *(short8*)&dXb[row * 32 + (l & 3) * 8] = *(const short8*)&Xt[xsrc];
#endif
    }
  };

  stageT(0, 0);
  for (int ci = 0; ci < 8; ++ci) {
    __syncthreads();  // drains tile-ci DMA; lgkm-drains prior reads (WAR)
    if (ci < 7) stageT((ci + 1) * 32, (ci + 1) & 1);
    const char* base = smem + (ci & 1) * 24576;
    const short* lWh = (const short*)base;
    const short* lWl = (const short*)(base + 8192);
    const short* lXb = (const short*)(base + 16384);

    short8 ah[4], al[4], bx[4];
#pragma unroll
    for (int ot = 0; ot < 4; ++ot) {
      int ar = wo + 16 * ot + l15;
      int sl = (quad ^ ((ar >> 1) & 3)) * 8;
      ah[ot] = *(const short8*)&lWh[ar * 32 + sl];
      al[ot] = *(const short8*)&lWl[ar * 32 + sl];
    }
#pragma unroll
    for (int nt = 0; nt < 4; ++nt) {
      int br = wn + 16 * nt + l15;
      int sl = (quad ^ ((br >> 1) & 3)) * 8;
      bx[nt] = *(const short8*)&lXb[br * 32 + sl];
    }
#pragma unroll
    for (int ot = 0; ot < 4; ++ot)
#pragma unroll
      for (int nt = 0; nt < 4; ++nt) {
        acc[ot][nt] =
            __builtin_amdgcn_mfma_f32_16x16x32_bf16(al[ot], bx[nt], acc[ot][nt], 0, 0, 0);
        acc[ot][nt] =
            __builtin_amdgcn_mfma_f32_16x16x32_bf16(ah[ot], bx[nt], acc[ot][nt], 0, 0, 0);
      }
  }

  if (isq) {
    // Q epilogue: LDS-stage the wave's 64x64 tile ([n][o]), then 8 coalesced
    // 128B row-pieces per wave.
    __syncthreads();  // all waves done reading main-loop tiles; reuse as slabs
    short (*qt)[72] = (short (*)[72])(smem + w * 9216);
#pragma unroll
    for (int nt = 0; nt < 4; ++nt)
#pragma unroll
      for (int ot = 0; ot < 4; ++ot) {
        short4v pk;
#pragma unroll
        for (int r = 0; r < 4; ++r) pk[r] = bf16r(CQ_ * acc[ot][nt][r]);
        *(short4v*)&qt[16 * nt + l15][16 * ot + 4 * quad] = pk;
      }
#pragma unroll
    for (int it = 0; it < 8; ++it) {
      int nr = 8 * it + (l >> 3);
      int c8 = (l & 7) * 8;
      *(short8*)&qb[((size_t)b * 2048 + n0 + wn + nr) * 512 + o0 + wo + c8] =
          *(const short8*)&qt[nr][c8];
    }
  } else if (o0 < 512) {
    // K part: one head per wave (64 ch) x one 64-m chunk; -2*CQ scale.
    // Stage swizzled tile in LDS, then 8 coalesced 1KB stores.
    const int head = (o0 + wo) >> 6;
    const int bh = b * 8 + head;
    const int chunk = (n0 + wn) >> 6;
    __syncthreads();  // all waves done reading main-loop tiles; reuse as slabs
    short (*kt)[72] = (short (*)[72])(smem + w * 9216);
    float k2p[4] = {0.f, 0.f, 0.f, 0.f};
#pragma unroll
    for (int nt = 0; nt < 4; ++nt) {
      int mrow = 16 * nt + l15;
      int sw = mrow & 7;
#pragma unroll
      for (int ot = 0; ot < 4; ++ot) {
        int d0 = 16 * ot + 4 * quad;
        short4v pk;
#pragma unroll
        for (int r = 0; r < 4; ++r) {
          short pv = bf16r(NEG2CQ_ * acc[ot][nt][r]);
          pk[r] = pv;
          float kr = bf2f(pv);
          k2p[nt] += kr * kr;
        }
        *(short4v*)&kt[mrow][(((d0 >> 3) ^ sw) << 3) + (d0 & 7)] = pk;
      }
    }
    size_t tbase = ((size_t)bh * 32 + chunk) * 4096;
#pragma unroll
    for (int it = 0; it < 8; ++it) {
      int mr = 8 * it + (l >> 3);
      int c8 = (l & 7) * 8;
      *(short8*)&kc[tbase + mr * 64 + c8] = *(const short8*)&kt[mr][c8];
    }
#pragma unroll
    for (int nt = 0; nt < 4; ++nt) {
      float s = k2p[nt];
      s += __shfl_xor(s, 16);
      s += __shfl_xor(s, 32);
      if (quad == 0) {
        int m = n0 + wn + 16 * nt + l15;
        int mv = maskp[b * 2048 + m];
        k2m[(size_t)bh * 2048 + m] = mv ? 0.25f * s : __builtin_inff();
      }
    }
  } else {
    // V part: f16, column permute (PV A-frag order) + group swizzle.
    // Stage permuted tile in LDS, then 8 coalesced 1KB stores.
    const int chv = o0 - 512 + wo;  // head*64
    const int bh = b * 8 + (chv >> 6);
    const int chunk = (n0 + wn) >> 6;
    __syncthreads();  // all waves done reading main-loop tiles; reuse as slabs
    _Float16 (*vt)[72] = (_Float16 (*)[72])(smem + w * 9216);
#pragma unroll
    for (int nt = 0; nt < 4; ++nt) {
      int jr = 16 * nt + l15;
      int jrem = jr & 31;
      int colp = 32 * (jr >> 5) + ((jrem >> 2) & 3) * 8 + (jrem >> 4) * 4 +
                 (jrem & 3);
#pragma unroll
      for (int ot = 0; ot < 4; ++ot)
#pragma unroll
        for (int r = 0; r < 4; ++r) {
          int drw = (16 * ot + 4 * quad + r) & 63;
          vt[drw][(((colp >> 3) ^ (drw & 7)) << 3) + (colp & 7)] =
              (_Float16)acc[ot][nt][r];
        }
    }
    size_t cbase = ((size_t)bh * 32 + chunk) * 4096;
#pragma unroll
    for (int it = 0; it < 8; ++it) {
      int dr = 8 * it + (l >> 3);
      int c8 = (l & 7) * 8;
      *(half8*)&vc[cbase + dr * 64 + c8] = *(const half8*)&vt[dr][c8];
    }
  }
}

// ---------------------------------------------------------------------------
// Kernel 3: L2-distance flash attention (exact R3 body -- FROZEN).
// 8 waves / 512 threads per block: wave (wr,jh) = (w>>1, w&1); wr picks the
// 16 q-rows, jh picks the j-half (32 of 64) of each chunk. 8 waves/SIMD at
// 32KB LDS (4 blocks/CU). |C2| pre-folded into q/k/k2m, so inner loop is
// exp2(-sqrt(max(a,eps))). PV is ONE mfma_f32_16x16x32_f16 per dt.
// HISTORY: R2 (cross-chunk dbuf+pipeline) spilled -> 352us; R5 (lean
// pipeline) 76.6us; R6 (k2 prefetch) 81us. The simple form is fastest
// (69.9us); the compiler's schedule beats all source-level reorderings.
// ---------------------------------------------------------------------------
__global__ __launch_bounds__(512, 8) void attn_kernel(
    const short* __restrict__ qb, const short* __restrict__ kc,
    const _Float16* __restrict__ vc, const float* __restrict__ k2m,
    short* __restrict__ attn_t) {
  const int bid = blockIdx.x;
  const int rr = bid & 7, qq = bid >> 3;  // rr ~ XCD
  const int bh = rr * 4 + (qq >> 5);      // 4 bh per XCD
  const int iblk = qq & 31;
  const int h = bh & 7, b = bh >> 3;
  const int i0 = iblk * 64;

  const int tid = threadIdx.x;
  const int w = tid >> 6, l = tid & 63, quad = l >> 4, l15 = l & 15;
  const int wr = w >> 1, jh = w & 1;

  __shared__ __align__(16) short sbuf[2][2][4096];  // [K/V][dbuf][8KB]

  const short* qrow =
      qb + ((size_t)b * 2048 + i0 + 16 * wr + l15) * 512 + h * 64;
  const short* kcb = kc + (size_t)bh * 32 * 4096;
  const _Float16* vcb = vc + (size_t)bh * 32 * 4096;
  const float* k2b = k2m + (size_t)bh * 2048;

  // Q^T B-fragments (n=i=l15, k=d=8*quad+jj) + q2 (per-lane scalar, CQ^2-scaled)
  short8 qa0 = *(const short8*)&qrow[8 * quad];
  short8 qa1 = *(const short8*)&qrow[32 + 8 * quad];
  float q2p = 0.f;
#pragma unroll
  for (int jj = 0; jj < 8; ++jj) {
    float f0 = bf2f(qa0[jj]), f1 = bf2f(qa1[jj]);
    q2p += f0 * f0 + f1 * f1;
  }
  q2p += __shfl_xor(q2p, 16);
  q2p += __shfl_xor(q2p, 32);
  const float q2c = q2p;

  floatx4 accO[4];
#pragma unroll
  for (int dt = 0; dt < 4; ++dt)
#pragma unroll
    for (int r = 0; r < 4; ++r) accO[dt][r] = 0.f;
  float lsum = 0.f;

  const int sx = l15 & 7;  // swizzle key

  auto stage = [&](int c, int p) {
    const short* ks = kcb + (size_t)c * 4096 + w * 512 + l * 8;
    const _Float16* vs = vcb + (size_t)c * 4096 + w * 512 + l * 8;
#ifdef HAS_DMA
    __builtin_amdgcn_global_load_lds((gvoid_t*)ks,
                                     (lvoid_t*)&sbuf[0][p][w * 512], 16, 0, 0);
    __builtin_amdgcn_global_load_lds((gvoid_t*)vs,
                                     (lvoid_t*)&sbuf[1][p][w * 512], 16, 0, 0);
#else
    *(short8*)&sbuf[0][p][w * 512 + l * 8] = *(const short8*)ks;
    *(half8*)&((_Float16*)sbuf[1][p])[w * 512 + l * 8] = *(const half8*)vs;
#endif
  };

  stage(0, 0);
  for (int c = 0; c < 32; ++c) {
    __syncthreads();  // drains chunk-c DMA (vmcnt(0) before barrier)
    if (c < 31) stage(c + 1, (c + 1) & 1);
    const int p = c & 1;

    half8 pb;
#pragma unroll
    for (int jt = 0; jt < 2; ++jt) {
      float4 k2v = *(const float4*)&k2b[c * 64 + jh * 32 + 16 * jt + 4 * quad];
      const short* kr = &sbuf[0][p][(jh * 32 + 16 * jt + l15) * 64];
      short8 k0 = *(const short8*)&kr[(quad ^ sx) << 3];
      short8 k1 = *(const short8*)&kr[((quad + 4) ^ sx) << 3];
      floatx4 a;  // accumulator pre-loaded with q2 + k2 (both CQ^2-scaled)
      a[0] = q2c + k2v.x;
      a[1] = q2c + k2v.y;
      a[2] = q2c + k2v.z;
      a[3] = q2c + k2v.w;
      __builtin_amdgcn_s_setprio(1);
      a = __builtin_amdgcn_mfma_f32_16x16x32_bf16(k0, qa0, a, 0, 0, 0);
      a = __builtin_amdgcn_mfma_f32_16x16x32_bf16(k1, qa1, a, 0, 0, 0);
      __builtin_amdgcn_s_setprio(0);
#pragma unroll
      for (int r = 0; r < 4; ++r) {
        float s = __builtin_amdgcn_sqrtf(fmaxf(a[r], EPS2_));
        float pv = __builtin_amdgcn_exp2f(-s);  // neg is a free input modifier
        lsum += pv;
        pb[4 * jt + r] = (_Float16)pv;
      }
    }

    __builtin_amdgcn_s_setprio(1);
#pragma unroll
    for (int dt = 0; dt < 4; ++dt) {
      const _Float16* vr = (const _Float16*)&sbuf[1][p][(16 * dt + l15) * 64];
      half8 hh = *(const half8*)&vr[((quad + 4 * jh) ^ sx) << 3];
      accO[dt] =
          __builtin_amdgcn_mfma_f32_16x16x32_f16(hh, pb, accO[dt], 0, 0, 0);
    }
    __builtin_amdgcn_s_setprio(0);
  }

  // Merge jh=1 partials into jh=0 through LDS (buffers are dead now).
  __syncthreads();
  float* scr = (float*)sbuf;  // 4 waves * 64 lanes * 17 floats = 17408B < 32KB
  const int sidx = (wr * 64 + l) * 17;
  if (jh) {
#pragma unroll
    for (int dt = 0; dt < 4; ++dt)
#pragma unroll
      for (int r = 0; r < 4; ++r) scr[sidx + dt * 4 + r] = accO[dt][r];
    scr[sidx + 16] = lsum;
  }
  __syncthreads();
  if (!jh) {
#pragma unroll
    for (int dt = 0; dt < 4; ++dt)
#pragma unroll
      for (int r = 0; r < 4; ++r) accO[dt][r] += scr[sidx + dt * 4 + r];
    lsum += scr[sidx + 16];
    lsum += __shfl_xor(lsum, 16);
    lsum += __shfl_xor(lsum, 32);
    float rl = 1.0f / lsum;
    size_t base = ((size_t)b * 2048 + i0 + 16 * wr + l15) * 512 + h * 64;
#pragma unroll
    for (int dt = 0; dt < 4; ++dt) {
      short4v pk;
#pragma unroll
      for (int r = 0; r < 4; ++r) pk[r] = bf16r(accO[dt][r] * rl);
      *(short4v*)&attn_t[base + 16 * dt + 4 * quad] = pk;
    }
  }
}

// ---------------------------------------------------------------------------
// Kernel 4: out-projection MFMA GEMM.
// R11: DMA staging (same swizzle scheme as qkv) + attn-style 1-barrier
// double buffer (2x12KB); store epilogue staged through per-wave LDS slabs
// -> 4 coalesced float4 row-stores per thread (was 16 stores forming 64B
// segments). 64o x 64n tiles, grid (32,4,B) = 512 blocks = 2 blocks/CU.
// 4 waves as 2x2: wave tile 32o x 32n, acc[2][2]. LDS 24KB.
// ---------------------------------------------------------------------------
__global__ __launch_bounds__(256) void outproj_kernel(
    const short* __restrict__ whi, const short* __restrict__ wlo,
    const short* __restrict__ Xt, float* __restrict__ Yf) {
  const int b = blockIdx.z;
  const int n0 = blockIdx.x * 64;
  const int o0 = blockIdx.y * 64;
  const int tid = threadIdx.x;
  const int w = tid >> 6, l = tid & 63, quad = l >> 4, l15 = l & 15;
  const int wo = (w >> 1) * 32, wn = (w & 1) * 32;

  // dbuf p at smem+p*12288: dWh +0, dWl +4096, dXb +8192 (each [64][32]).
  // Store epilogue: 4 wave slabs of float[32][36] = 18432B (overlay).
  __shared__ __align__(16) char smem[24576];

  floatx4 acc[2][2];
#pragma unroll
  for (int ot = 0; ot < 2; ++ot)
#pragma unroll
    for (int nt = 0; nt < 2; ++nt)
#pragma unroll
      for (int r = 0; r < 4; ++r) acc[ot][nt][r] = 0.f;

  auto stageT = [&](int c0, int p) {
    char* base = smem + p * 12288;
    short* dWh = (short*)base;
    short* dWl = (short*)(base + 4096);
    short* dXb = (short*)(base + 8192);
    int r0 = w * 16;
    int row = r0 + (l >> 2);
    int chunk = (l & 3) ^ ((row >> 1) & 3);
    size_t wsrc = (size_t)(o0 + row) * 512 + c0 + chunk * 8;
    size_t xsrc = ((size_t)b * 2048 + n0 + row) * 512 + c0 + chunk * 8;
#ifdef HAS_DMA
    __builtin_amdgcn_global_load_lds((gvoid_t*)&whi[wsrc],
                                     (lvoid_t*)&dWh[r0 * 32], 16, 0, 0);
    __builtin_amdgcn_global_load_lds((gvoid_t*)&wlo[wsrc],
                                     (lvoid_t*)&dWl[r0 * 32], 16, 0, 0);
    __builtin_amdgcn_global_load_lds((gvoid_t*)&Xt[xsrc],
                                     (lvoid_t*)&dXb[r0 * 32], 16, 0, 0);
#else
    *(short8*)&dWh[row * 32 + (l & 3) * 8] = *(const short8*)&whi[wsrc];
    *(short8*)&dWl[row * 32 + (l & 3) * 8] = *(const short8*)&wlo[wsrc];
    *(short8*)&dXb[row * 32 + (l & 3) * 8] = *(const short8*)&Xt[xsrc];
#endif
  };

  stageT(0, 0);
  for (int ci = 0; ci < 16; ++ci) {
    __syncthreads();  // drains tile-ci DMA; lgkm-drains prior reads (WAR)
    if (ci < 15) stageT((ci + 1) * 32, (ci + 1) & 1);
    const char* base = smem + (ci & 1) * 12288;
    const short* lWh = (const short*)base;
    const short* lWl = (const short*)(base + 4096);
    const short* lXb = (const short*)(base + 8192);

    short8 ah[2], al[2], bx[2];
#pragma unroll
    for (int ot = 0; ot < 2; ++ot) {
      int ar = wo + 16 * ot + l15;
      int sl = (quad ^ ((ar >> 1) & 3)) * 8;
      ah[ot] = *(const short8*)&lWh[ar * 32 + sl];
      al[ot] = *(const short8*)&lWl[ar * 32 + sl];
    }
#pragma unroll
    for (int nt = 0; nt < 2; ++nt) {
      int br = wn + 16 * nt + l15;
      int sl = (quad ^ ((br >> 1) & 3)) * 8;
      bx[nt] = *(const short8*)&lXb[br * 32 + sl];
    }
#pragma unroll
    for (int ot = 0; ot < 2; ++ot)
#pragma unroll
      for (int nt = 0; nt < 2; ++nt) {
        acc[ot][nt] =
            __builtin_amdgcn_mfma_f32_16x16x32_bf16(al[ot], bx[nt], acc[ot][nt], 0, 0, 0);
        acc[ot][nt] =
            __builtin_amdgcn_mfma_f32_16x16x32_bf16(ah[ot], bx[nt], acc[ot][nt], 0, 0, 0);
      }
  }

  // Store epilogue: stage the wave's 32o x 32n fp32 tile in its LDS slab,
  // then 4 coalesced float4 row-stores per thread (8 rows x 128B per inst).
  __syncthreads();  // all waves done reading main-loop tiles; reuse as slabs
  float (*yt)[36] = (float (*)[36])(smem + w * 4608);
#pragma unroll
  for (int ot = 0; ot < 2; ++ot)
#pragma unroll
    for (int nt = 0; nt < 2; ++nt)
#pragma unroll
      for (int r = 0; r < 4; ++r)
        yt[16 * ot + 4 * quad + r][16 * nt + l15] = acc[ot][nt][r];
#pragma unroll
  for (int it = 0; it < 4; ++it) {
    int orow = 8 * it + (l >> 3);
    int c4 = (l & 7) * 4;
    *(float4*)&Yf[((size_t)b * 256 + o0 + wo + orow) * 2048 + n0 + wn + c4] =
        *(const float4*)&yt[orow][c4];
  }
}

// ---------------------------------------------------------------------------
extern "C" void kernel_launch(void* const* d_in, const int* in_sizes, int n_in,
                              void* d_out, int out_size, void* d_ws,
                              size_t ws_size, hipStream_t stream) {
  const float* fmap = (const float*)d_in[0];
  const float* context = (const float*)d_in[1];
  const int* mask = (const int*)d_in[2];
  const float* gamma = (const float*)d_in[3];
  const float* gamma_ctx = (const float*)d_in[4];
  const float* Wq = (const float*)d_in[5];
  const float* Wkv = (const float*)d_in[6];
  const float* Wout = (const float*)d_in[7];
  float* out = (float*)d_out;

  char* ws = (char*)d_ws;
  short* fmap_t = (short*)ws;                 // 4 MB
  short* ctx_t = fmap_t + 2097152;            // 4 MB
  short* qb = ctx_t + 2097152;                // 8 MB
  short* kc = qb + 4194304;                   // 8 MB (-2CQ*K, swizzled tiles)
  _Float16* vc = (_Float16*)(kc + 4194304);   // 8 MB (f16, permuted tiles)
  short* attn_t = (short*)(vc + 4194304);     // 8 MB
  float* k2m = (float*)(attn_t + 4194304);    // 256 KB
  short* whi = (short*)(k2m + 65536);         // 1 MB
  short* wlo = whi + 524288;                  // 1 MB

  preproc_kernel<<<dim3(1024), 256, 0, stream>>>(
      Wq, Wkv, Wout, gamma, gamma_ctx, whi, wlo, fmap, context, fmap_t, ctx_t);
  qkv_gemm_kernel<<<dim3(16, 12, B_), 256, 0, stream>>>(
      whi, wlo, fmap_t, ctx_t, qb, kc, vc, mask, k2m);
  attn_kernel<<<dim3(1024), 512, 0, stream>>>(qb, kc, vc, k2m, attn_t);
  outproj_kernel<<<dim3(32, 4, B_), 256, 0, stream>>>(whi + 393216,
                                                      wlo + 393216, attn_t,
                                                      out);
}

// Round 12
// 177.015 us; speedup vs baseline: 1.0286x; 1.0286x over previous
//
#include <hip/hip_runtime.h>
#include <hip/hip_bf16.h>

// Problem constants
#define B_ 4
#define DIM_ 256
#define N_ 2048
#define M_ 2048
#define HEADS_ 8
#define DHEAD_ 64
#define DINNER_ 512

typedef __attribute__((ext_vector_type(8))) short short8;
typedef __attribute__((ext_vector_type(4))) short short4v;
typedef __attribute__((ext_vector_type(4))) float floatx4;
typedef __attribute__((ext_vector_type(4))) _Float16 half4;
typedef __attribute__((ext_vector_type(8))) _Float16 half8;

#if defined(__has_builtin)
#if __has_builtin(__builtin_amdgcn_global_load_lds)
#define HAS_DMA 1
#endif
#endif

typedef __attribute__((address_space(1))) const void gvoid_t;
typedef __attribute__((address_space(3))) void lvoid_t;

// |C2| = 0.125 * log2(e); folded into Q and K bf16 planes so attention's
// inner loop computes pv = exp2(-sqrt(d2')) with zero extra multiplies.
#define CQ_ 0.18033688011112042f
#define NEG2CQ_ (-0.36067376022224084f)
#define EPS2_ 3.25213893e-14f  // 1e-12 * CQ^2

__device__ inline short bf16r(float x) {  // RNE f32->bf16 (bit form)
  unsigned u = __float_as_uint(x);
  unsigned r = (u + 0x7fffu + ((u >> 16) & 1u)) >> 16;
  return (short)r;
}
__device__ inline float bf2f(short b) {
  return __uint_as_float(((unsigned)(unsigned short)b) << 16);
}

// ---------------------------------------------------------------------------
// Kernel 0 (fused preproc): R12 rebalanced -- 512 blocks x 512 threads.
// bid<256 -> W split (flattened: every thread useful); bid>=256 -> channel
// RMSNorm->bf16 transpose with 8 waves/block (was 4 waves, 1-deep grid:
// colnorm blocks were the latency-exposed tail of the old 1024x256 launch).
// ---------------------------------------------------------------------------
__global__ __launch_bounds__(512) void preproc_kernel(
    const float* __restrict__ Wq, const float* __restrict__ Wkv,
    const float* __restrict__ Wout, const float* __restrict__ gamma,
    const float* __restrict__ gctx, short* __restrict__ whi,
    short* __restrict__ wlo, const float* __restrict__ xf,
    const float* __restrict__ xc, short* __restrict__ xtf,
    short* __restrict__ xtc) {
  const int bid = blockIdx.x;
  const int tid = threadIdx.x;

  __shared__ float4 red4[32][16];
  __shared__ float scl[64];
  __shared__ float t[64][65];

  if (bid < 256) {
    // ---- W split part: flat over 131072 float4 groups ----
    int flat = bid * 512 + tid;
    int y, lg;
    if (flat < 32768) { y = 0; lg = flat; }
    else if (flat < 98304) { y = 1; lg = flat - 32768; }
    else { y = 2; lg = flat - 98304; }
    const int goff[3] = {0, 131072, 393216};  // element offset in planes
    const float* W = (y == 0) ? Wq : (y == 1) ? Wkv : Wout;
    const int cmask = (y == 2) ? 511 : 255;
    int e0 = lg * 4;
    int c = e0 & cmask;
    float4 wv = *(const float4*)&W[e0];
    if (y < 2) {
      const float* g = (y == 0) ? gamma : gctx;
      float4 g4 = *(const float4*)&g[c];
      wv.x *= g4.x; wv.y *= g4.y; wv.z *= g4.z; wv.w *= g4.w;
    }
    float vv[4] = {wv.x, wv.y, wv.z, wv.w};
    short4v hi, lo;
#pragma unroll
    for (int e = 0; e < 4; ++e) {
      short hb = bf16r(vv[e]);
      hi[e] = hb;
      lo[e] = bf16r(vv[e] - bf2f(hb));
    }
    *(short4v*)&whi[goff[y] + e0] = hi;
    *(short4v*)&wlo[goff[y] + e0] = lo;
    return;
  }

  // ---- colnorm part (512 threads, float4-vectorized) ----
  const int cid = bid - 256;              // 0..255
  const int NN = 2048;
  const int z = cid >> 7;                 // 0..1
  const int b = (cid >> 5) & 3;           // 0..3
  const int xblk = cid & 31;              // 0..31
  const float* x = (z == 0) ? xf : xc;
  short* xt = (z == 0) ? xtf : xtc;
  const int tx4 = tid & 15, tyc = tid >> 4;  // n-quad 0..15, ch-lane 0..31
  const int n0 = xblk * 64;
  const float* xb = x + (size_t)b * 256 * NN;

  float4 ssq4 = {0.f, 0.f, 0.f, 0.f};
  for (int c = tyc; c < 256; c += 32) {  // 8 iters
    float4 v = *(const float4*)&xb[(size_t)c * NN + n0 + tx4 * 4];
    ssq4.x += v.x * v.x; ssq4.y += v.y * v.y;
    ssq4.z += v.z * v.z; ssq4.w += v.w * v.w;
  }
  red4[tyc][tx4] = ssq4;
  __syncthreads();
  if (tid < 16) {
    float4 s = red4[0][tid];
#pragma unroll
    for (int g = 1; g < 32; ++g) {
      float4 v = red4[g][tid];
      s.x += v.x; s.y += v.y; s.z += v.z; s.w += v.w;
    }
    scl[tid * 4 + 0] = 16.0f / fmaxf(sqrtf(s.x), 1e-12f);
    scl[tid * 4 + 1] = 16.0f / fmaxf(sqrtf(s.y), 1e-12f);
    scl[tid * 4 + 2] = 16.0f / fmaxf(sqrtf(s.z), 1e-12f);
    scl[tid * 4 + 3] = 16.0f / fmaxf(sqrtf(s.w), 1e-12f);
  }
  const int row = tid >> 3, cg = tid & 7;  // row 0..63, ch-group 0..7
  for (int c0 = 0; c0 < 256; c0 += 64) {
    __syncthreads();
    for (int cc = tyc; cc < 64; cc += 32) {  // 2 iters
      float4 v = *(const float4*)&xb[(size_t)(c0 + cc) * NN + n0 + tx4 * 4];
      t[cc][tx4 * 4 + 0] = v.x;
      t[cc][tx4 * 4 + 1] = v.y;
      t[cc][tx4 * 4 + 2] = v.z;
      t[cc][tx4 * 4 + 3] = v.w;
    }
    __syncthreads();
    float sc = scl[row];
    short8 ov;
#pragma unroll
    for (int e = 0; e < 8; ++e) ov[e] = bf16r(t[cg * 8 + e][row] * sc);
    *(short8*)&xt[((size_t)b * NN + n0 + row) * 256 + c0 + cg * 8] = ov;
  }
}

// ---------------------------------------------------------------------------
// Kernel 2: fused Q + KV projection MFMA GEMM (R11 form).
// grid (16, 12, B): y<4 -> q-proj; y>=4 -> kv-proj (K-part / V-part).
// 1-barrier double-buffered DMA staging; LDS-staged coalesced epilogues.
// ---------------------------------------------------------------------------
__global__ __launch_bounds__(256) void qkv_gemm_kernel(
    const short* __restrict__ whi, const short* __restrict__ wlo,
    const short* __restrict__ fmap_t, const short* __restrict__ ctx_t,
    short* __restrict__ qb, short* __restrict__ kc, _Float16* __restrict__ vc,
    const int* __restrict__ maskp, float* __restrict__ k2m) {
  const int b = blockIdx.z;
  const int y = blockIdx.y;
  const bool isq = (y < 4);
  const int o0 = (isq ? y : y - 4) * 128;
  const int n0 = blockIdx.x * 128;
  const short* Wh = whi + (isq ? 0 : 131072);
  const short* Wl = wlo + (isq ? 0 : 131072);
  const short* Xt = isq ? fmap_t : ctx_t;

  const int tid = threadIdx.x;
  const int w = tid >> 6, l = tid & 63, quad = l >> 4, l15 = l & 15;
  const int wo = (w >> 1) * 64, wn = (w & 1) * 64;

  // dbuf p at smem+p*24576: lWh +0, lWl +8192, lXb +16384 (each [128][32]).
  // Epilogue: 4 wave slabs of [64][72] shorts = 36864B (overlay).
  __shared__ __align__(16) char smem[49152];

  floatx4 acc[4][4];
#pragma unroll
  for (int ot = 0; ot < 4; ++ot)
#pragma unroll
    for (int nt = 0; nt < 4; ++nt)
#pragma unroll
      for (int r = 0; r < 4; ++r) acc[ot][nt][r] = 0.f;

  auto stageT = [&](int c0, int p) {
    char* base = smem + p * 24576;
    short* dWh = (short*)base;
    short* dWl = (short*)(base + 8192);
    short* dXb = (short*)(base + 16384);
#pragma unroll
    for (int half = 0; half < 2; ++half) {
      int r0 = w * 32 + half * 16;
      int row = r0 + (l >> 2);
      int chunk = (l & 3) ^ ((row >> 1) & 3);
      size_t wsrc = (size_t)(o0 + row) * 256 + c0 + chunk * 8;
      size_t xsrc = ((size_t)b * 2048 + n0 + row) * 256 + c0 + chunk * 8;
#ifdef HAS_DMA
      __builtin_amdgcn_global_load_lds((gvoid_t*)&Wh[wsrc],
                                       (lvoid_t*)&dWh[r0 * 32], 16, 0, 0);
      __builtin_amdgcn_global_load_lds((gvoid_t*)&Wl[wsrc],
                                       (lvoid_t*)&dWl[r0 * 32], 16, 0, 0);
      __builtin_amdgcn_global_load_lds((gvoid_t*)&Xt[xsrc],
                                       (lvoid_t*)&dXb[r0 * 32], 16, 0, 0);
#else
      *(short8*)&dWh[row * 32 + (l & 3) * 8] = *(const short8*)&Wh[wsrc];
      *(short8*)&dWl[row * 32 + (l & 3) * 8] = *(const short8*)&Wl[wsrc];
      *(short8*)&dXb[row * 32 + (l & 3) * 8] = *(const short8*)&Xt[xsrc];
#endif
    }
  };

  stageT(0, 0);
  for (int ci = 0; ci < 8; ++ci) {
    __syncthreads();  // drains tile-ci DMA; lgkm-drains prior reads (WAR)
    if (ci < 7) stageT((ci + 1) * 32, (ci + 1) & 1);
    const char* base = smem + (ci & 1) * 24576;
    const short* lWh = (const short*)base;
    const short* lWl = (const short*)(base + 8192);
    const short* lXb = (const short*)(base + 16384);

    short8 ah[4], al[4], bx[4];
#pragma unroll
    for (int ot = 0; ot < 4; ++ot) {
      int ar = wo + 16 * ot + l15;
      int sl = (quad ^ ((ar >> 1) & 3)) * 8;
      ah[ot] = *(const short8*)&lWh[ar * 32 + sl];
      al[ot] = *(const short8*)&lWl[ar * 32 + sl];
    }
#pragma unroll
    for (int nt = 0; nt < 4; ++nt) {
      int br = wn + 16 * nt + l15;
      int sl = (quad ^ ((br >> 1) & 3)) * 8;
      bx[nt] = *(const short8*)&lXb[br * 32 + sl];
    }
#pragma unroll
    for (int ot = 0; ot < 4; ++ot)
#pragma unroll
      for (int nt = 0; nt < 4; ++nt) {
        acc[ot][nt] =
            __builtin_amdgcn_mfma_f32_16x16x32_bf16(al[ot], bx[nt], acc[ot][nt], 0, 0, 0);
        acc[ot][nt] =
            __builtin_amdgcn_mfma_f32_16x16x32_bf16(ah[ot], bx[nt], acc[ot][nt], 0, 0, 0);
      }
  }

  if (isq) {
    // Q epilogue: LDS-stage the wave's 64x64 tile ([n][o]), then 8 coalesced
    // 128B row-pieces per wave.
    __syncthreads();  // all waves done reading main-loop tiles; reuse as slabs
    short (*qt)[72] = (short (*)[72])(smem + w * 9216);
#pragma unroll
    for (int nt = 0; nt < 4; ++nt)
#pragma unroll
      for (int ot = 0; ot < 4; ++ot) {
        short4v pk;
#pragma unroll
        for (int r = 0; r < 4; ++r) pk[r] = bf16r(CQ_ * acc[ot][nt][r]);
        *(short4v*)&qt[16 * nt + l15][16 * ot + 4 * quad] = pk;
      }
#pragma unroll
    for (int it = 0; it < 8; ++it) {
      int nr = 8 * it + (l >> 3);
      int c8 = (l & 7) * 8;
      *(short8*)&qb[((size_t)b * 2048 + n0 + wn + nr) * 512 + o0 + wo + c8] =
          *(const short8*)&qt[nr][c8];
    }
  } else if (o0 < 512) {
    // K part: one head per wave (64 ch) x one 64-m chunk; -2*CQ scale.
    // Stage swizzled tile in LDS, then 8 coalesced 1KB stores.
    const int head = (o0 + wo) >> 6;
    const int bh = b * 8 + head;
    const int chunk = (n0 + wn) >> 6;
    __syncthreads();  // all waves done reading main-loop tiles; reuse as slabs
    short (*kt)[72] = (short (*)[72])(smem + w * 9216);
    float k2p[4] = {0.f, 0.f, 0.f, 0.f};
#pragma unroll
    for (int nt = 0; nt < 4; ++nt) {
      int mrow = 16 * nt + l15;
      int sw = mrow & 7;
#pragma unroll
      for (int ot = 0; ot < 4; ++ot) {
        int d0 = 16 * ot + 4 * quad;
        short4v pk;
#pragma unroll
        for (int r = 0; r < 4; ++r) {
          short pv = bf16r(NEG2CQ_ * acc[ot][nt][r]);
          pk[r] = pv;
          float kr = bf2f(pv);
          k2p[nt] += kr * kr;
        }
        *(short4v*)&kt[mrow][(((d0 >> 3) ^ sw) << 3) + (d0 & 7)] = pk;
      }
    }
    size_t tbase = ((size_t)bh * 32 + chunk) * 4096;
#pragma unroll
    for (int it = 0; it < 8; ++it) {
      int mr = 8 * it + (l >> 3);
      int c8 = (l & 7) * 8;
      *(short8*)&kc[tbase + mr * 64 + c8] = *(const short8*)&kt[mr][c8];
    }
#pragma unroll
    for (int nt = 0; nt < 4; ++nt) {
      float s = k2p[nt];
      s += __shfl_xor(s, 16);
      s += __shfl_xor(s, 32);
      if (quad == 0) {
        int m = n0 + wn + 16 * nt + l15;
        int mv = maskp[b * 2048 + m];
        k2m[(size_t)bh * 2048 + m] = mv ? 0.25f * s : __builtin_inff();
      }
    }
  } else {
    // V part: f16, column permute (PV A-frag order) + group swizzle.
    // Stage permuted tile in LDS, then 8 coalesced 1KB stores.
    const int chv = o0 - 512 + wo;  // head*64
    const int bh = b * 8 + (chv >> 6);
    const int chunk = (n0 + wn) >> 6;
    __syncthreads();  // all waves done reading main-loop tiles; reuse as slabs
    _Float16 (*vt)[72] = (_Float16 (*)[72])(smem + w * 9216);
#pragma unroll
    for (int nt = 0; nt < 4; ++nt) {
      int jr = 16 * nt + l15;
      int jrem = jr & 31;
      int colp = 32 * (jr >> 5) + ((jrem >> 2) & 3) * 8 + (jrem >> 4) * 4 +
                 (jrem & 3);
#pragma unroll
      for (int ot = 0; ot < 4; ++ot)
#pragma unroll
        for (int r = 0; r < 4; ++r) {
          int drw = (16 * ot + 4 * quad + r) & 63;
          vt[drw][(((colp >> 3) ^ (drw & 7)) << 3) + (colp & 7)] =
              (_Float16)acc[ot][nt][r];
        }
    }
    size_t cbase = ((size_t)bh * 32 + chunk) * 4096;
#pragma unroll
    for (int it = 0; it < 8; ++it) {
      int dr = 8 * it + (l >> 3);
      int c8 = (l & 7) * 8;
      *(half8*)&vc[cbase + dr * 64 + c8] = *(const half8*)&vt[dr][c8];
    }
  }
}

// ---------------------------------------------------------------------------
// Kernel 3: L2-distance flash attention (R3 body; R12: k2 via DMA+LDS).
// 8 waves / 512 threads per block: wave (wr,jh) = (w>>1, w&1). 8 waves/SIMD
// at 33.3KB LDS (4 blocks/CU). |C2| pre-folded into q/k/k2m.
// R12 change: the two per-chunk k2 global float4 loads (L2 latency on the
// QK critical path) are replaced by one width-4 global_load_lds in stage()
// (wave 0, 256B/chunk into k2buf) + broadcast ds_read_b128 -- drained by
// the same barrier as K/V, so the latency rides the existing pipeline.
// Compute order is UNCHANGED (R2/R5/R6 lesson: do not reorder compute).
// ---------------------------------------------------------------------------
__global__ __launch_bounds__(512, 8) void attn_kernel(
    const short* __restrict__ qb, const short* __restrict__ kc,
    const _Float16* __restrict__ vc, const float* __restrict__ k2m,
    short* __restrict__ attn_t) {
  const int bid = blockIdx.x;
  const int rr = bid & 7, qq = bid >> 3;  // rr ~ XCD
  const int bh = rr * 4 + (qq >> 5);      // 4 bh per XCD
  const int iblk = qq & 31;
  const int h = bh & 7, b = bh >> 3;
  const int i0 = iblk * 64;

  const int tid = threadIdx.x;
  const int w = tid >> 6, l = tid & 63, quad = l >> 4, l15 = l & 15;
  const int wr = w >> 1, jh = w & 1;

  __shared__ __align__(16) short sbuf[2][2][4096];  // [K/V][dbuf][8KB]
  __shared__ __align__(16) float k2buf[2][64];      // k2 chunk side-buffer

  const short* qrow =
      qb + ((size_t)b * 2048 + i0 + 16 * wr + l15) * 512 + h * 64;
  const short* kcb = kc + (size_t)bh * 32 * 4096;
  const _Float16* vcb = vc + (size_t)bh * 32 * 4096;
  const float* k2b = k2m + (size_t)bh * 2048;

  // Q^T B-fragments (n=i=l15, k=d=8*quad+jj) + q2 (per-lane scalar, CQ^2-scaled)
  short8 qa0 = *(const short8*)&qrow[8 * quad];
  short8 qa1 = *(const short8*)&qrow[32 + 8 * quad];
  float q2p = 0.f;
#pragma unroll
  for (int jj = 0; jj < 8; ++jj) {
    float f0 = bf2f(qa0[jj]), f1 = bf2f(qa1[jj]);
    q2p += f0 * f0 + f1 * f1;
  }
  q2p += __shfl_xor(q2p, 16);
  q2p += __shfl_xor(q2p, 32);
  const float q2c = q2p;

  floatx4 accO[4];
#pragma unroll
  for (int dt = 0; dt < 4; ++dt)
#pragma unroll
    for (int r = 0; r < 4; ++r) accO[dt][r] = 0.f;
  float lsum = 0.f;

  const int sx = l15 & 7;  // swizzle key

  auto stage = [&](int c, int p) {
    const short* ks = kcb + (size_t)c * 4096 + w * 512 + l * 8;
    const _Float16* vs = vcb + (size_t)c * 4096 + w * 512 + l * 8;
#ifdef HAS_DMA
    __builtin_amdgcn_global_load_lds((gvoid_t*)ks,
                                     (lvoid_t*)&sbuf[0][p][w * 512], 16, 0, 0);
    __builtin_amdgcn_global_load_lds((gvoid_t*)vs,
                                     (lvoid_t*)&sbuf[1][p][w * 512], 16, 0, 0);
    if (w == 0)
      __builtin_amdgcn_global_load_lds((gvoid_t*)(k2b + c * 64 + l),
                                       (lvoid_t*)&k2buf[p][0], 4, 0, 0);
#else
    *(short8*)&sbuf[0][p][w * 512 + l * 8] = *(const short8*)ks;
    *(half8*)&((_Float16*)sbuf[1][p])[w * 512 + l * 8] = *(const half8*)vs;
    if (w == 0) k2buf[p][l] = k2b[c * 64 + l];
#endif
  };

  stage(0, 0);
  for (int c = 0; c < 32; ++c) {
    __syncthreads();  // drains chunk-c DMA (vmcnt(0) before barrier)
    if (c < 31) stage(c + 1, (c + 1) & 1);
    const int p = c & 1;

    half8 pb;
#pragma unroll
    for (int jt = 0; jt < 2; ++jt) {
      float4 k2v = *(const float4*)&k2buf[p][jh * 32 + 16 * jt + 4 * quad];
      const short* kr = &sbuf[0][p][(jh * 32 + 16 * jt + l15) * 64];
      short8 k0 = *(const short8*)&kr[(quad ^ sx) << 3];
      short8 k1 = *(const short8*)&kr[((quad + 4) ^ sx) << 3];
      floatx4 a;  // accumulator pre-loaded with q2 + k2 (both CQ^2-scaled)
      a[0] = q2c + k2v.x;
      a[1] = q2c + k2v.y;
      a[2] = q2c + k2v.z;
      a[3] = q2c + k2v.w;
      __builtin_amdgcn_s_setprio(1);
      a = __builtin_amdgcn_mfma_f32_16x16x32_bf16(k0, qa0, a, 0, 0, 0);
      a = __builtin_amdgcn_mfma_f32_16x16x32_bf16(k1, qa1, a, 0, 0, 0);
      __builtin_amdgcn_s_setprio(0);
#pragma unroll
      for (int r = 0; r < 4; ++r) {
        float s = __builtin_amdgcn_sqrtf(fmaxf(a[r], EPS2_));
        float pv = __builtin_amdgcn_exp2f(-s);  // neg is a free input modifier
        lsum += pv;
        pb[4 * jt + r] = (_Float16)pv;
      }
    }

    __builtin_amdgcn_s_setprio(1);
#pragma unroll
    for (int dt = 0; dt < 4; ++dt) {
      const _Float16* vr = (const _Float16*)&sbuf[1][p][(16 * dt + l15) * 64];
      half8 hh = *(const half8*)&vr[((quad + 4 * jh) ^ sx) << 3];
      accO[dt] =
          __builtin_amdgcn_mfma_f32_16x16x32_f16(hh, pb, accO[dt], 0, 0, 0);
    }
    __builtin_amdgcn_s_setprio(0);
  }

  // Merge jh=1 partials into jh=0 through LDS (buffers are dead now).
  __syncthreads();
  float* scr = (float*)sbuf;  // 4 waves * 64 lanes * 17 floats = 17408B < 32KB
  const int sidx = (wr * 64 + l) * 17;
  if (jh) {
#pragma unroll
    for (int dt = 0; dt < 4; ++dt)
#pragma unroll
      for (int r = 0; r < 4; ++r) scr[sidx + dt * 4 + r] = accO[dt][r];
    scr[sidx + 16] = lsum;
  }
  __syncthreads();
  if (!jh) {
#pragma unroll
    for (int dt = 0; dt < 4; ++dt)
#pragma unroll
      for (int r = 0; r < 4; ++r) accO[dt][r] += scr[sidx + dt * 4 + r];
    lsum += scr[sidx + 16];
    lsum += __shfl_xor(lsum, 16);
    lsum += __shfl_xor(lsum, 32);
    float rl = 1.0f / lsum;
    size_t base = ((size_t)b * 2048 + i0 + 16 * wr + l15) * 512 + h * 64;
#pragma unroll
    for (int dt = 0; dt < 4; ++dt) {
      short4v pk;
#pragma unroll
      for (int r = 0; r < 4; ++r) pk[r] = bf16r(accO[dt][r] * rl);
      *(short4v*)&attn_t[base + 16 * dt + 4 * quad] = pk;
    }
  }
}

// ---------------------------------------------------------------------------
// Kernel 4: out-projection MFMA GEMM (R11 form).
// DMA staging + 1-barrier double buffer; LDS-staged coalesced store
// epilogue. 64o x 64n tiles, grid (32,4,B) = 512 blocks = 2 blocks/CU.
// ---------------------------------------------------------------------------
__global__ __launch_bounds__(256) void outproj_kernel(
    const short* __restrict__ whi, const short* __restrict__ wlo,
    const short* __restrict__ Xt, float* __restrict__ Yf) {
  const int b = blockIdx.z;
  const int n0 = blockIdx.x * 64;
  const int o0 = blockIdx.y * 64;
  const int tid = threadIdx.x;
  const int w = tid >> 6, l = tid & 63, quad = l >> 4, l15 = l & 15;
  const int wo = (w >> 1) * 32, wn = (w & 1) * 32;

  // dbuf p at smem+p*12288: dWh +0, dWl +4096, dXb +8192 (each [64][32]).
  // Store epilogue: 4 wave slabs of float[32][36] = 18432B (overlay).
  __shared__ __align__(16) char smem[24576];

  floatx4 acc[2][2];
#pragma unroll
  for (int ot = 0; ot < 2; ++ot)
#pragma unroll
    for (int nt = 0; nt < 2; ++nt)
#pragma unroll
      for (int r = 0; r < 4; ++r) acc[ot][nt][r] = 0.f;

  auto stageT = [&](int c0, int p) {
    char* base = smem + p * 12288;
    short* dWh = (short*)base;
    short* dWl = (short*)(base + 4096);
    short* dXb = (short*)(base + 8192);
    int r0 = w * 16;
    int row = r0 + (l >> 2);
    int chunk = (l & 3) ^ ((row >> 1) & 3);
    size_t wsrc = (size_t)(o0 + row) * 512 + c0 + chunk * 8;
    size_t xsrc = ((size_t)b * 2048 + n0 + row) * 512 + c0 + chunk * 8;
#ifdef HAS_DMA
    __builtin_amdgcn_global_load_lds((gvoid_t*)&whi[wsrc],
                                     (lvoid_t*)&dWh[r0 * 32], 16, 0, 0);
    __builtin_amdgcn_global_load_lds((gvoid_t*)&wlo[wsrc],
                                     (lvoid_t*)&dWl[r0 * 32], 16, 0, 0);
    __builtin_amdgcn_global_load_lds((gvoid_t*)&Xt[xsrc],
                                     (lvoid_t*)&dXb[r0 * 32], 16, 0, 0);
#else
    *(short8*)&dWh[row * 32 + (l & 3) * 8] = *(const short8*)&whi[wsrc];
    *(short8*)&dWl[row * 32 + (l & 3) * 8] = *(const short8*)&wlo[wsrc];
    *(short8*)&dXb[row * 32 + (l & 3) * 8] = *(const short8*)&Xt[xsrc];
#endif
  };

  stageT(0, 0);
  for (int ci = 0; ci < 16; ++ci) {
    __syncthreads();  // drains tile-ci DMA; lgkm-drains prior reads (WAR)
    if (ci < 15) stageT((ci + 1) * 32, (ci + 1) & 1);
    const char* base = smem + (ci & 1) * 12288;
    const short* lWh = (const short*)base;
    const short* lWl = (const short*)(base + 4096);
    const short* lXb = (const short*)(base + 8192);

    short8 ah[2], al[2], bx[2];
#pragma unroll
    for (int ot = 0; ot < 2; ++ot) {
      int ar = wo + 16 * ot + l15;
      int sl = (quad ^ ((ar >> 1) & 3)) * 8;
      ah[ot] = *(const short8*)&lWh[ar * 32 + sl];
      al[ot] = *(const short8*)&lWl[ar * 32 + sl];
    }
#pragma unroll
    for (int nt = 0; nt < 2; ++nt) {
      int br = wn + 16 * nt + l15;
      int sl = (quad ^ ((br >> 1) & 3)) * 8;
      bx[nt] = *(const short8*)&lXb[br * 32 + sl];
    }
#pragma unroll
    for (int ot = 0; ot < 2; ++ot)
#pragma unroll
      for (int nt = 0; nt < 2; ++nt) {
        acc[ot][nt] =
            __builtin_amdgcn_mfma_f32_16x16x32_bf16(al[ot], bx[nt], acc[ot][nt], 0, 0, 0);
        acc[ot][nt] =
            __builtin_amdgcn_mfma_f32_16x16x32_bf16(ah[ot], bx[nt], acc[ot][nt], 0, 0, 0);
      }
  }

  // Store epilogue: stage the wave's 32o x 32n fp32 tile in its LDS slab,
  // then 4 coalesced float4 row-stores per thread (8 rows x 128B per inst).
  __syncthreads();  // all waves done reading main-loop tiles; reuse as slabs
  float (*yt)[36] = (float (*)[36])(smem + w * 4608);
#pragma unroll
  for (int ot = 0; ot < 2; ++ot)
#pragma unroll
    for (int nt = 0; nt < 2; ++nt)
#pragma unroll
      for (int r = 0; r < 4; ++r)
        yt[16 * ot + 4 * quad + r][16 * nt + l15] = acc[ot][nt][r];
#pragma unroll
  for (int it = 0; it < 4; ++it) {
    int orow = 8 * it + (l >> 3);
    int c4 = (l & 7) * 4;
    *(float4*)&Yf[((size_t)b * 256 + o0 + wo + orow) * 2048 + n0 + wn + c4] =
        *(const float4*)&yt[orow][c4];
  }
}

// ---------------------------------------------------------------------------
extern "C" void kernel_launch(void* const* d_in, const int* in_sizes, int n_in,
                              void* d_out, int out_size, void* d_ws,
                              size_t ws_size, hipStream_t stream) {
  const float* fmap = (const float*)d_in[0];
  const float* context = (const float*)d_in[1];
  const int* mask = (const int*)d_in[2];
  const float* gamma = (const float*)d_in[3];
  const float* gamma_ctx = (const float*)d_in[4];
  const float* Wq = (const float*)d_in[5];
  const float* Wkv = (const float*)d_in[6];
  const float* Wout = (const float*)d_in[7];
  float* out = (float*)d_out;

  char* ws = (char*)d_ws;
  short* fmap_t = (short*)ws;                 // 4 MB
  short* ctx_t = fmap_t + 2097152;            // 4 MB
  short* qb = ctx_t + 2097152;                // 8 MB
  short* kc = qb + 4194304;                   // 8 MB (-2CQ*K, swizzled tiles)
  _Float16* vc = (_Float16*)(kc + 4194304);   // 8 MB (f16, permuted tiles)
  short* attn_t = (short*)(vc + 4194304);     // 8 MB
  float* k2m = (float*)(attn_t + 4194304);    // 256 KB
  short* whi = (short*)(k2m + 65536);         // 1 MB
  short* wlo = whi + 524288;                  // 1 MB

  preproc_kernel<<<dim3(512), 512, 0, stream>>>(
      Wq, Wkv, Wout, gamma, gamma_ctx, whi, wlo, fmap, context, fmap_t, ctx_t);
  qkv_gemm_kernel<<<dim3(16, 12, B_), 256, 0, stream>>>(
      whi, wlo, fmap_t, ctx_t, qb, kc, vc, mask, k2m);
  attn_kernel<<<dim3(1024), 512, 0, stream>>>(qb, kc, vc, k2m, attn_t);
  outproj_kernel<<<dim3(32, 4, B_), 256, 0, stream>>>(whi + 393216,
                                                      wlo + 393216, attn_t,
                                                      out);
}

// Round 14
// 171.225 us; speedup vs baseline: 1.0634x; 1.0338x over previous
//
#include <hip/hip_runtime.h>
#include <hip/hip_bf16.h>

// Problem constants
#define B_ 4
#define DIM_ 256
#define N_ 2048
#define M_ 2048
#define HEADS_ 8
#define DHEAD_ 64
#define DINNER_ 512

typedef __attribute__((ext_vector_type(8))) short short8;
typedef __attribute__((ext_vector_type(4))) short short4v;
typedef __attribute__((ext_vector_type(4))) float floatx4;
typedef __attribute__((ext_vector_type(4))) _Float16 half4;
typedef __attribute__((ext_vector_type(8))) _Float16 half8;

#if defined(__has_builtin)
#if __has_builtin(__builtin_amdgcn_global_load_lds)
#define HAS_DMA 1
#endif
#endif

typedef __attribute__((address_space(1))) const void gvoid_t;
typedef __attribute__((address_space(3))) void lvoid_t;

// |C2| = 0.125 * log2(e); folded into Q and K bf16 planes so attention's
// inner loop computes pv = exp2(-sqrt(d2')) with zero extra multiplies.
#define CQ_ 0.18033688011112042f
#define NEG2CQ_ (-0.36067376022224084f)
#define EPS2_ 3.25213893e-14f  // 1e-12 * CQ^2

__device__ inline short bf16r(float x) {  // RNE f32->bf16 (bit form)
  unsigned u = __float_as_uint(x);
  unsigned r = (u + 0x7fffu + ((u >> 16) & 1u)) >> 16;
  return (short)r;
}
__device__ inline float bf2f(short b) {
  return __uint_as_float(((unsigned)(unsigned short)b) << 16);
}

// ---------------------------------------------------------------------------
// Kernel 0 (fused preproc): 512 blocks x 512 threads (R12, verified).
// bid<256 -> W split (flattened); bid>=256 -> channel RMSNorm->bf16
// transpose with 8 waves/block.
// ---------------------------------------------------------------------------
__global__ __launch_bounds__(512) void preproc_kernel(
    const float* __restrict__ Wq, const float* __restrict__ Wkv,
    const float* __restrict__ Wout, const float* __restrict__ gamma,
    const float* __restrict__ gctx, short* __restrict__ whi,
    short* __restrict__ wlo, const float* __restrict__ xf,
    const float* __restrict__ xc, short* __restrict__ xtf,
    short* __restrict__ xtc) {
  const int bid = blockIdx.x;
  const int tid = threadIdx.x;

  __shared__ float4 red4[32][16];
  __shared__ float scl[64];
  __shared__ float t[64][65];

  if (bid < 256) {
    // ---- W split part: flat over 131072 float4 groups ----
    int flat = bid * 512 + tid;
    int y, lg;
    if (flat < 32768) { y = 0; lg = flat; }
    else if (flat < 98304) { y = 1; lg = flat - 32768; }
    else { y = 2; lg = flat - 98304; }
    const int goff[3] = {0, 131072, 393216};  // element offset in planes
    const float* W = (y == 0) ? Wq : (y == 1) ? Wkv : Wout;
    const int cmask = (y == 2) ? 511 : 255;
    int e0 = lg * 4;
    int c = e0 & cmask;
    float4 wv = *(const float4*)&W[e0];
    if (y < 2) {
      const float* g = (y == 0) ? gamma : gctx;
      float4 g4 = *(const float4*)&g[c];
      wv.x *= g4.x; wv.y *= g4.y; wv.z *= g4.z; wv.w *= g4.w;
    }
    float vv[4] = {wv.x, wv.y, wv.z, wv.w};
    short4v hi, lo;
#pragma unroll
    for (int e = 0; e < 4; ++e) {
      short hb = bf16r(vv[e]);
      hi[e] = hb;
      lo[e] = bf16r(vv[e] - bf2f(hb));
    }
    *(short4v*)&whi[goff[y] + e0] = hi;
    *(short4v*)&wlo[goff[y] + e0] = lo;
    return;
  }

  // ---- colnorm part (512 threads, float4-vectorized) ----
  const int cid = bid - 256;              // 0..255
  const int NN = 2048;
  const int z = cid >> 7;                 // 0..1
  const int b = (cid >> 5) & 3;           // 0..3
  const int xblk = cid & 31;              // 0..31
  const float* x = (z == 0) ? xf : xc;
  short* xt = (z == 0) ? xtf : xtc;
  const int tx4 = tid & 15, tyc = tid >> 4;  // n-quad 0..15, ch-lane 0..31
  const int n0 = xblk * 64;
  const float* xb = x + (size_t)b * 256 * NN;

  float4 ssq4 = {0.f, 0.f, 0.f, 0.f};
  for (int c = tyc; c < 256; c += 32) {  // 8 iters
    float4 v = *(const float4*)&xb[(size_t)c * NN + n0 + tx4 * 4];
    ssq4.x += v.x * v.x; ssq4.y += v.y * v.y;
    ssq4.z += v.z * v.z; ssq4.w += v.w * v.w;
  }
  red4[tyc][tx4] = ssq4;
  __syncthreads();
  if (tid < 16) {
    float4 s = red4[0][tid];
#pragma unroll
    for (int g = 1; g < 32; ++g) {
      float4 v = red4[g][tid];
      s.x += v.x; s.y += v.y; s.z += v.z; s.w += v.w;
    }
    scl[tid * 4 + 0] = 16.0f / fmaxf(sqrtf(s.x), 1e-12f);
    scl[tid * 4 + 1] = 16.0f / fmaxf(sqrtf(s.y), 1e-12f);
    scl[tid * 4 + 2] = 16.0f / fmaxf(sqrtf(s.z), 1e-12f);
    scl[tid * 4 + 3] = 16.0f / fmaxf(sqrtf(s.w), 1e-12f);
  }
  const int row = tid >> 3, cg = tid & 7;  // row 0..63, ch-group 0..7
  for (int c0 = 0; c0 < 256; c0 += 64) {
    __syncthreads();
    for (int cc = tyc; cc < 64; cc += 32) {  // 2 iters
      float4 v = *(const float4*)&xb[(size_t)(c0 + cc) * NN + n0 + tx4 * 4];
      t[cc][tx4 * 4 + 0] = v.x;
      t[cc][tx4 * 4 + 1] = v.y;
      t[cc][tx4 * 4 + 2] = v.z;
      t[cc][tx4 * 4 + 3] = v.w;
    }
    __syncthreads();
    float sc = scl[row];
    short8 ov;
#pragma unroll
    for (int e = 0; e < 8; ++e) ov[e] = bf16r(t[cg * 8 + e][row] * sc);
    *(short8*)&xt[((size_t)b * NN + n0 + row) * 256 + c0 + cg * 8] = ov;
  }
}

// ---------------------------------------------------------------------------
// Kernel 2: fused Q + KV projection MFMA GEMM (R11/R12 form, verified).
// grid (16, 12, B): y<4 -> q-proj; y>=4 -> kv-proj (K-part / V-part).
// 1-barrier double-buffered DMA staging; LDS-staged coalesced epilogues.
// ---------------------------------------------------------------------------
__global__ __launch_bounds__(256) void qkv_gemm_kernel(
    const short* __restrict__ whi, const short* __restrict__ wlo,
    const short* __restrict__ fmap_t, const short* __restrict__ ctx_t,
    short* __restrict__ qb, short* __restrict__ kc, _Float16* __restrict__ vc,
    const int* __restrict__ maskp, float* __restrict__ k2m) {
  const int b = blockIdx.z;
  const int y = blockIdx.y;
  const bool isq = (y < 4);
  const int o0 = (isq ? y : y - 4) * 128;
  const int n0 = blockIdx.x * 128;
  const short* Wh = whi + (isq ? 0 : 131072);
  const short* Wl = wlo + (isq ? 0 : 131072);
  const short* Xt = isq ? fmap_t : ctx_t;

  const int tid = threadIdx.x;
  const int w = tid >> 6, l = tid & 63, quad = l >> 4, l15 = l & 15;
  const int wo = (w >> 1) * 64, wn = (w & 1) * 64;

  // dbuf p at smem+p*24576: lWh +0, lWl +8192, lXb +16384 (each [128][32]).
  // Epilogue: 4 wave slabs of [64][72] shorts = 36864B (overlay).
  __shared__ __align__(16) char smem[49152];

  floatx4 acc[4][4];
#pragma unroll
  for (int ot = 0; ot < 4; ++ot)
#pragma unroll
    for (int nt = 0; nt < 4; ++nt)
#pragma unroll
      for (int r = 0; r < 4; ++r) acc[ot][nt][r] = 0.f;

  auto stageT = [&](int c0, int p) {
    char* base = smem + p * 24576;
    short* dWh = (short*)base;
    short* dWl = (short*)(base + 8192);
    short* dXb = (short*)(base + 16384);
#pragma unroll
    for (int half = 0; half < 2; ++half) {
      int r0 = w * 32 + half * 16;
      int row = r0 + (l >> 2);
      int chunk = (l & 3) ^ ((row >> 1) & 3);
      size_t wsrc = (size_t)(o0 + row) * 256 + c0 + chunk * 8;
      size_t xsrc = ((size_t)b * 2048 + n0 + row) * 256 + c0 + chunk * 8;
#ifdef HAS_DMA
      __builtin_amdgcn_global_load_lds((gvoid_t*)&Wh[wsrc],
                                       (lvoid_t*)&dWh[r0 * 32], 16, 0, 0);
      __builtin_amdgcn_global_load_lds((gvoid_t*)&Wl[wsrc],
                                       (lvoid_t*)&dWl[r0 * 32], 16, 0, 0);
      __builtin_amdgcn_global_load_lds((gvoid_t*)&Xt[xsrc],
                                       (lvoid_t*)&dXb[r0 * 32], 16, 0, 0);
#else
      *(short8*)&dWh[row * 32 + (l & 3) * 8] = *(const short8*)&Wh[wsrc];
      *(short8*)&dWl[row * 32 + (l & 3) * 8] = *(const short8*)&Wl[wsrc];
      *(short8*)&dXb[row * 32 + (l & 3) * 8] = *(const short8*)&Xt[xsrc];
#endif
    }
  };

  stageT(0, 0);
  for (int ci = 0; ci < 8; ++ci) {
    __syncthreads();  // drains tile-ci DMA; lgkm-drains prior reads (WAR)
    if (ci < 7) stageT((ci + 1) * 32, (ci + 1) & 1);
    const char* base = smem + (ci & 1) * 24576;
    const short* lWh = (const short*)base;
    const short* lWl = (const short*)(base + 8192);
    const short* lXb = (const short*)(base + 16384);

    short8 ah[4], al[4], bx[4];
#pragma unroll
    for (int ot = 0; ot < 4; ++ot) {
      int ar = wo + 16 * ot + l15;
      int sl = (quad ^ ((ar >> 1) & 3)) * 8;
      ah[ot] = *(const short8*)&lWh[ar * 32 + sl];
      al[ot] = *(const short8*)&lWl[ar * 32 + sl];
    }
#pragma unroll
    for (int nt = 0; nt < 4; ++nt) {
      int br = wn + 16 * nt + l15;
      int sl = (quad ^ ((br >> 1) & 3)) * 8;
      bx[nt] = *(const short8*)&lXb[br * 32 + sl];
    }
#pragma unroll
    for (int ot = 0; ot < 4; ++ot)
#pragma unroll
      for (int nt = 0; nt < 4; ++nt) {
        acc[ot][nt] =
            __builtin_amdgcn_mfma_f32_16x16x32_bf16(al[ot], bx[nt], acc[ot][nt], 0, 0, 0);
        acc[ot][nt] =
            __builtin_amdgcn_mfma_f32_16x16x32_bf16(ah[ot], bx[nt], acc[ot][nt], 0, 0, 0);
      }
  }

  if (isq) {
    // Q epilogue: LDS-stage the wave's 64x64 tile ([n][o]), then 8 coalesced
    // 128B row-pieces per wave.
    __syncthreads();  // all waves done reading main-loop tiles; reuse as slabs
    short (*qt)[72] = (short (*)[72])(smem + w * 9216);
#pragma unroll
    for (int nt = 0; nt < 4; ++nt)
#pragma unroll
      for (int ot = 0; ot < 4; ++ot) {
        short4v pk;
#pragma unroll
        for (int r = 0; r < 4; ++r) pk[r] = bf16r(CQ_ * acc[ot][nt][r]);
        *(short4v*)&qt[16 * nt + l15][16 * ot + 4 * quad] = pk;
      }
#pragma unroll
    for (int it = 0; it < 8; ++it) {
      int nr = 8 * it + (l >> 3);
      int c8 = (l & 7) * 8;
      *(short8*)&qb[((size_t)b * 2048 + n0 + wn + nr) * 512 + o0 + wo + c8] =
          *(const short8*)&qt[nr][c8];
    }
  } else if (o0 < 512) {
    // K part: one head per wave (64 ch) x one 64-m chunk; -2*CQ scale.
    // Stage swizzled tile in LDS, then 8 coalesced 1KB stores.
    const int head = (o0 + wo) >> 6;
    const int bh = b * 8 + head;
    const int chunk = (n0 + wn) >> 6;
    __syncthreads();  // all waves done reading main-loop tiles; reuse as slabs
    short (*kt)[72] = (short (*)[72])(smem + w * 9216);
    float k2p[4] = {0.f, 0.f, 0.f, 0.f};
#pragma unroll
    for (int nt = 0; nt < 4; ++nt) {
      int mrow = 16 * nt + l15;
      int sw = mrow & 7;
#pragma unroll
      for (int ot = 0; ot < 4; ++ot) {
        int d0 = 16 * ot + 4 * quad;
        short4v pk;
#pragma unroll
        for (int r = 0; r < 4; ++r) {
          short pv = bf16r(NEG2CQ_ * acc[ot][nt][r]);
          pk[r] = pv;
          float kr = bf2f(pv);
          k2p[nt] += kr * kr;
        }
        *(short4v*)&kt[mrow][(((d0 >> 3) ^ sw) << 3) + (d0 & 7)] = pk;
      }
    }
    size_t tbase = ((size_t)bh * 32 + chunk) * 4096;
#pragma unroll
    for (int it = 0; it < 8; ++it) {
      int mr = 8 * it + (l >> 3);
      int c8 = (l & 7) * 8;
      *(short8*)&kc[tbase + mr * 64 + c8] = *(const short8*)&kt[mr][c8];
    }
#pragma unroll
    for (int nt = 0; nt < 4; ++nt) {
      float s = k2p[nt];
      s += __shfl_xor(s, 16);
      s += __shfl_xor(s, 32);
      if (quad == 0) {
        int m = n0 + wn + 16 * nt + l15;
        int mv = maskp[b * 2048 + m];
        k2m[(size_t)bh * 2048 + m] = mv ? 0.25f * s : __builtin_inff();
      }
    }
  } else {
    // V part: f16, column permute (PV A-frag order) + group swizzle.
    // Stage permuted tile in LDS, then 8 coalesced 1KB stores.
    const int chv = o0 - 512 + wo;  // head*64
    const int bh = b * 8 + (chv >> 6);
    const int chunk = (n0 + wn) >> 6;
    __syncthreads();  // all waves done reading main-loop tiles; reuse as slabs
    _Float16 (*vt)[72] = (_Float16 (*)[72])(smem + w * 9216);
#pragma unroll
    for (int nt = 0; nt < 4; ++nt) {
      int jr = 16 * nt + l15;
      int jrem = jr & 31;
      int colp = 32 * (jr >> 5) + ((jrem >> 2) & 3) * 8 + (jrem >> 4) * 4 +
                 (jrem & 3);
#pragma unroll
      for (int ot = 0; ot < 4; ++ot)
#pragma unroll
        for (int r = 0; r < 4; ++r) {
          int drw = (16 * ot + 4 * quad + r) & 63;
          vt[drw][(((colp >> 3) ^ (drw & 7)) << 3) + (colp & 7)] =
              (_Float16)acc[ot][nt][r];
        }
    }
    size_t cbase = ((size_t)bh * 32 + chunk) * 4096;
#pragma unroll
    for (int it = 0; it < 8; ++it) {
      int dr = 8 * it + (l >> 3);
      int c8 = (l & 7) * 8;
      *(half8*)&vc[cbase + dr * 64 + c8] = *(const half8*)&vt[dr][c8];
    }
  }
}

// ---------------------------------------------------------------------------
// Kernel 3: L2-distance flash attention (exact R11 body -- FROZEN).
// 8 waves / 512 threads per block: wave (wr,jh) = (w>>1, w&1). 8 waves/SIMD
// at 32KB LDS (4 blocks/CU). |C2| pre-folded into q/k/k2m; PV is ONE
// mfma_f32_16x16x32_f16 per dt.
// HISTORY: R2 (cross-chunk dbuf+pipeline) spilled -> 352us; R5 (lean
// pipeline) 76.6us; R6 (k2 reg prefetch) 81us; R12 (k2 via DMA+LDS) 71us;
// R13 (cooperative outproj fusion) FAILED correctness (grid.sync no-op
// under graph capture). This simple form is fastest (69.2us).
// ---------------------------------------------------------------------------
__global__ __launch_bounds__(512, 8) void attn_kernel(
    const short* __restrict__ qb, const short* __restrict__ kc,
    const _Float16* __restrict__ vc, const float* __restrict__ k2m,
    short* __restrict__ attn_t) {
  const int bid = blockIdx.x;
  const int rr = bid & 7, qq = bid >> 3;  // rr ~ XCD
  const int bh = rr * 4 + (qq >> 5);      // 4 bh per XCD
  const int iblk = qq & 31;
  const int h = bh & 7, b = bh >> 3;
  const int i0 = iblk * 64;

  const int tid = threadIdx.x;
  const int w = tid >> 6, l = tid & 63, quad = l >> 4, l15 = l & 15;
  const int wr = w >> 1, jh = w & 1;

  __shared__ __align__(16) short sbuf[2][2][4096];  // [K/V][dbuf][8KB]

  const short* qrow =
      qb + ((size_t)b * 2048 + i0 + 16 * wr + l15) * 512 + h * 64;
  const short* kcb = kc + (size_t)bh * 32 * 4096;
  const _Float16* vcb = vc + (size_t)bh * 32 * 4096;
  const float* k2b = k2m + (size_t)bh * 2048;

  // Q^T B-fragments (n=i=l15, k=d=8*quad+jj) + q2 (per-lane scalar, CQ^2-scaled)
  short8 qa0 = *(const short8*)&qrow[8 * quad];
  short8 qa1 = *(const short8*)&qrow[32 + 8 * quad];
  float q2p = 0.f;
#pragma unroll
  for (int jj = 0; jj < 8; ++jj) {
    float f0 = bf2f(qa0[jj]), f1 = bf2f(qa1[jj]);
    q2p += f0 * f0 + f1 * f1;
  }
  q2p += __shfl_xor(q2p, 16);
  q2p += __shfl_xor(q2p, 32);
  const float q2c = q2p;

  floatx4 accO[4];
#pragma unroll
  for (int dt = 0; dt < 4; ++dt)
#pragma unroll
    for (int r = 0; r < 4; ++r) accO[dt][r] = 0.f;
  float lsum = 0.f;

  const int sx = l15 & 7;  // swizzle key

  auto stage = [&](int c, int p) {
    const short* ks = kcb + (size_t)c * 4096 + w * 512 + l * 8;
    const _Float16* vs = vcb + (size_t)c * 4096 + w * 512 + l * 8;
#ifdef HAS_DMA
    __builtin_amdgcn_global_load_lds((gvoid_t*)ks,
                                     (lvoid_t*)&sbuf[0][p][w * 512], 16, 0, 0);
    __builtin_amdgcn_global_load_lds((gvoid_t*)vs,
                                     (lvoid_t*)&sbuf[1][p][w * 512], 16, 0, 0);
#else
    *(short8*)&sbuf[0][p][w * 512 + l * 8] = *(const short8*)ks;
    *(half8*)&((_Float16*)sbuf[1][p])[w * 512 + l * 8] = *(const half8*)vs;
#endif
  };

  stage(0, 0);
  for (int c = 0; c < 32; ++c) {
    __syncthreads();  // drains chunk-c DMA (vmcnt(0) before barrier)
    if (c < 31) stage(c + 1, (c + 1) & 1);
    const int p = c & 1;

    half8 pb;
#pragma unroll
    for (int jt = 0; jt < 2; ++jt) {
      float4 k2v = *(const float4*)&k2b[c * 64 + jh * 32 + 16 * jt + 4 * quad];
      const short* kr = &sbuf[0][p][(jh * 32 + 16 * jt + l15) * 64];
      short8 k0 = *(const short8*)&kr[(quad ^ sx) << 3];
      short8 k1 = *(const short8*)&kr[((quad + 4) ^ sx) << 3];
      floatx4 a;  // accumulator pre-loaded with q2 + k2 (both CQ^2-scaled)
      a[0] = q2c + k2v.x;
      a[1] = q2c + k2v.y;
      a[2] = q2c + k2v.z;
      a[3] = q2c + k2v.w;
      __builtin_amdgcn_s_setprio(1);
      a = __builtin_amdgcn_mfma_f32_16x16x32_bf16(k0, qa0, a, 0, 0, 0);
      a = __builtin_amdgcn_mfma_f32_16x16x32_bf16(k1, qa1, a, 0, 0, 0);
      __builtin_amdgcn_s_setprio(0);
#pragma unroll
      for (int r = 0; r < 4; ++r) {
        float s = __builtin_amdgcn_sqrtf(fmaxf(a[r], EPS2_));
        float pv = __builtin_amdgcn_exp2f(-s);  // neg is a free input modifier
        lsum += pv;
        pb[4 * jt + r] = (_Float16)pv;
      }
    }

    __builtin_amdgcn_s_setprio(1);
#pragma unroll
    for (int dt = 0; dt < 4; ++dt) {
      const _Float16* vr = (const _Float16*)&sbuf[1][p][(16 * dt + l15) * 64];
      half8 hh = *(const half8*)&vr[((quad + 4 * jh) ^ sx) << 3];
      accO[dt] =
          __builtin_amdgcn_mfma_f32_16x16x32_f16(hh, pb, accO[dt], 0, 0, 0);
    }
    __builtin_amdgcn_s_setprio(0);
  }

  // Merge jh=1 partials into jh=0 through LDS (buffers are dead now).
  __syncthreads();
  float* scr = (float*)sbuf;  // 4 waves * 64 lanes * 17 floats = 17408B < 32KB
  const int sidx = (wr * 64 + l) * 17;
  if (jh) {
#pragma unroll
    for (int dt = 0; dt < 4; ++dt)
#pragma unroll
      for (int r = 0; r < 4; ++r) scr[sidx + dt * 4 + r] = accO[dt][r];
    scr[sidx + 16] = lsum;
  }
  __syncthreads();
  if (!jh) {
#pragma unroll
    for (int dt = 0; dt < 4; ++dt)
#pragma unroll
      for (int r = 0; r < 4; ++r) accO[dt][r] += scr[sidx + dt * 4 + r];
    lsum += scr[sidx + 16];
    lsum += __shfl_xor(lsum, 16);
    lsum += __shfl_xor(lsum, 32);
    float rl = 1.0f / lsum;
    size_t base = ((size_t)b * 2048 + i0 + 16 * wr + l15) * 512 + h * 64;
#pragma unroll
    for (int dt = 0; dt < 4; ++dt) {
      short4v pk;
#pragma unroll
      for (int r = 0; r < 4; ++r) pk[r] = bf16r(accO[dt][r] * rl);
      *(short4v*)&attn_t[base + 16 * dt + 4 * quad] = pk;
    }
  }
}

// ---------------------------------------------------------------------------
// Kernel 4: out-projection MFMA GEMM (R11 form, verified).
// DMA staging + 1-barrier double buffer; LDS-staged coalesced store
// epilogue. 64o x 64n tiles, grid (32,4,B) = 512 blocks = 2 blocks/CU.
// ---------------------------------------------------------------------------
__global__ __launch_bounds__(256) void outproj_kernel(
    const short* __restrict__ whi, const short* __restrict__ wlo,
    const short* __restrict__ Xt, float* __restrict__ Yf) {
  const int b = blockIdx.z;
  const int n0 = blockIdx.x * 64;
  const int o0 = blockIdx.y * 64;
  const int tid = threadIdx.x;
  const int w = tid >> 6, l = tid & 63, quad = l >> 4, l15 = l & 15;
  const int wo = (w >> 1) * 32, wn = (w & 1) * 32;

  // dbuf p at smem+p*12288: dWh +0, dWl +4096, dXb +8192 (each [64][32]).
  // Store epilogue: 4 wave slabs of float[32][36] = 18432B (overlay).
  __shared__ __align__(16) char smem[24576];

  floatx4 acc[2][2];
#pragma unroll
  for (int ot = 0; ot < 2; ++ot)
#pragma unroll
    for (int nt = 0; nt < 2; ++nt)
#pragma unroll
      for (int r = 0; r < 4; ++r) acc[ot][nt][r] = 0.f;

  auto stageT = [&](int c0, int p) {
    char* base = smem + p * 12288;
    short* dWh = (short*)base;
    short* dWl = (short*)(base + 4096);
    short* dXb = (short*)(base + 8192);
    int r0 = w * 16;
    int row = r0 + (l >> 2);
    int chunk = (l & 3) ^ ((row >> 1) & 3);
    size_t wsrc = (size_t)(o0 + row) * 512 + c0 + chunk * 8;
    size_t xsrc = ((size_t)b * 2048 + n0 + row) * 512 + c0 + chunk * 8;
#ifdef HAS_DMA
    __builtin_amdgcn_global_load_lds((gvoid_t*)&whi[wsrc],
                                     (lvoid_t*)&dWh[r0 * 32], 16, 0, 0);
    __builtin_amdgcn_global_load_lds((gvoid_t*)&wlo[wsrc],
                                     (lvoid_t*)&dWl[r0 * 32], 16, 0, 0);
    __builtin_amdgcn_global_load_lds((gvoid_t*)&Xt[xsrc],
                                     (lvoid_t*)&dXb[r0 * 32], 16, 0, 0);
#else
    *(short8*)&dWh[row * 32 + (l & 3) * 8] = *(const short8*)&whi[wsrc];
    *(short8*)&dWl[row * 32 + (l & 3) * 8] = *(const short8*)&wlo[wsrc];
    *(short8*)&dXb[row * 32 + (l & 3) * 8] = *(const short8*)&Xt[xsrc];
#endif
  };

  stageT(0, 0);
  for (int ci = 0; ci < 16; ++ci) {
    __syncthreads();  // drains tile-ci DMA; lgkm-drains prior reads (WAR)
    if (ci < 15) stageT((ci + 1) * 32, (ci + 1) & 1);
    const char* base = smem + (ci & 1) * 12288;
    const short* lWh = (const short*)base;
    const short* lWl = (const short*)(base + 4096);
    const short* lXb = (const short*)(base + 8192);

    short8 ah[2], al[2], bx[2];
#pragma unroll
    for (int ot = 0; ot < 2; ++ot) {
      int ar = wo + 16 * ot + l15;
      int sl = (quad ^ ((ar >> 1) & 3)) * 8;
      ah[ot] = *(const short8*)&lWh[ar * 32 + sl];
      al[ot] = *(const short8*)&lWl[ar * 32 + sl];
    }
#pragma unroll
    for (int nt = 0; nt < 2; ++nt) {
      int br = wn + 16 * nt + l15;
      int sl = (quad ^ ((br >> 1) & 3)) * 8;
      bx[nt] = *(const short8*)&lXb[br * 32 + sl];
    }
#pragma unroll
    for (int ot = 0; ot < 2; ++ot)
#pragma unroll
      for (int nt = 0; nt < 2; ++nt) {
        acc[ot][nt] =
            __builtin_amdgcn_mfma_f32_16x16x32_bf16(al[ot], bx[nt], acc[ot][nt], 0, 0, 0);
        acc[ot][nt] =
            __builtin_amdgcn_mfma_f32_16x16x32_bf16(ah[ot], bx[nt], acc[ot][nt], 0, 0, 0);
      }
  }

  // Store epilogue: stage the wave's 32o x 32n fp32 tile in its LDS slab,
  // then 4 coalesced float4 row-stores per thread (8 rows x 128B per inst).
  __syncthreads();  // all waves done reading main-loop tiles; reuse as slabs
  float (*yt)[36] = (float (*)[36])(smem + w * 4608);
#pragma unroll
  for (int ot = 0; ot < 2; ++ot)
#pragma unroll
    for (int nt = 0; nt < 2; ++nt)
#pragma unroll
      for (int r = 0; r < 4; ++r)
        yt[16 * ot + 4 * quad + r][16 * nt + l15] = acc[ot][nt][r];
#pragma unroll
  for (int it = 0; it < 4; ++it) {
    int orow = 8 * it + (l >> 3);
    int c4 = (l & 7) * 4;
    *(float4*)&Yf[((size_t)b * 256 + o0 + wo + orow) * 2048 + n0 + wn + c4] =
        *(const float4*)&yt[orow][c4];
  }
}

// ---------------------------------------------------------------------------
extern "C" void kernel_launch(void* const* d_in, const int* in_sizes, int n_in,
                              void* d_out, int out_size, void* d_ws,
                              size_t ws_size, hipStream_t stream) {
  const float* fmap = (const float*)d_in[0];
  const float* context = (const float*)d_in[1];
  const int* mask = (const int*)d_in[2];
  const float* gamma = (const float*)d_in[3];
  const float* gamma_ctx = (const float*)d_in[4];
  const float* Wq = (const float*)d_in[5];
  const float* Wkv = (const float*)d_in[6];
  const float* Wout = (const float*)d_in[7];
  float* out = (float*)d_out;

  char* ws = (char*)d_ws;
  short* fmap_t = (short*)ws;                 // 4 MB
  short* ctx_t = fmap_t + 2097152;            // 4 MB
  short* qb = ctx_t + 2097152;                // 8 MB
  short* kc = qb + 4194304;                   // 8 MB (-2CQ*K, swizzled tiles)
  _Float16* vc = (_Float16*)(kc + 4194304);   // 8 MB (f16, permuted tiles)
  short* attn_t = (short*)(vc + 4194304);     // 8 MB
  float* k2m = (float*)(attn_t + 4194304);    // 256 KB
  short* whi = (short*)(k2m + 65536);         // 1 MB
  short* wlo = whi + 524288;                  // 1 MB

  preproc_kernel<<<dim3(512), 512, 0, stream>>>(
      Wq, Wkv, Wout, gamma, gamma_ctx, whi, wlo, fmap, context, fmap_t, ctx_t);
  qkv_gemm_kernel<<<dim3(16, 12, B_), 256, 0, stream>>>(
      whi, wlo, fmap_t, ctx_t, qb, kc, vc, mask, k2m);
  attn_kernel<<<dim3(1024), 512, 0, stream>>>(qb, kc, vc, k2m, attn_t);
  outproj_kernel<<<dim3(32, 4, B_), 256, 0, stream>>>(whi + 393216,
                                                      wlo + 393216, attn_t,
                                                      out);
}